// Round 7
// baseline (198.311 us; speedup 1.0000x reference)
//
#include <hip/hip_runtime.h>

// HarmonicFullyConnectedTensorProduct, lmax=2, MUL=64, B=1024, 11 paths.
// out[z,w,k] += sum_{u,v,m,n} x1[z,u,m] x2[z,v,n] W[p,w,u,v] C_p[m,n,k]
//
// Round 15: 1-WAVE WORKGROUPS. R13 (174.6us, tp 83) + R14 (phase-merge, LDS
// bloat -> occ 19%, tp 99) together falsified the occupancy-cap and
// barrier-count theories: the cost is the 4-wave barrier RENDEZVOUS (waves at
// different progress waiting for each other), hidden only by cross-block
// overlap. Fix: each 64-thread (1-wave) block owns a full (16z x 16u)
// sub-problem -> __syncthreads degenerates to a trivial single-wave waitcnt;
// zero cross-wave coupling; MFMA(u) overlaps tform(u+1) within the wave
// because acc is only read in the epilogue. Same op order -> bit-identical.
// 2816 blocks x 64thr; LDS <= 15872 (10 blk/CU); ~200 VGPR (8 waves/CU, all
// independent). x2 reg-hoisted except p2/p10/p6 (N1=5,K1>=3) which reload
// from L1 per z (avoids R10-style spill). Backend (partials layout, prep_w,
// reduce_out) identical to R13.

#define NTHREADS 256         // prep_w / reduce_out
#define TP_THREADS 64        // tp_main: one wave
#define SMEM_BYTES 15872     // max over paths (p2/p10)

typedef __attribute__((ext_vector_type(4))) float f32x4;
typedef __attribute__((ext_vector_type(8))) short s16x8;

__device__ __forceinline__ unsigned short f2bf(float x) {
    __bf16 b = (__bf16)x;
    union { __bf16 h; unsigned short u; } v;
    v.h = b;
    return v.u;
}

// ---------------- prep: W fp32 [p][w][u][v] -> bf16 [p][u][w][v] ----------------

__global__ __launch_bounds__(NTHREADS) void prep_w(const float* __restrict__ W,
                                                   unsigned short* __restrict__ Wb)
{
    int id = blockIdx.x * NTHREADS + threadIdx.x;   // (p,u,w,v4): 11*64*64*16
    int v4 = (id & 15) << 2;
    int w  = (id >> 4) & 63;
    int u  = (id >> 10) & 63;
    int p  = id >> 16;
    float4 f = *(const float4*)(W + (((size_t)p * 64 + w) * 64 + u) * 64 + v4);
    ushort4 h;
    h.x = f2bf(f.x); h.y = f2bf(f.y); h.z = f2bf(f.z); h.w = f2bf(f.w);
    *(ushort4*)(Wb + (((size_t)p * 64 + u) * 64 + w) * 64 + v4) = h;
}

// ---------------- main ----------------

struct KArgs {
    const float*          x1[3];
    const float*          x2[3];
    const unsigned short* Wb;
    const float*          C[11];
    float*                part[11];   // per-path partials [4 usub][K1][1024][64]
};

// One wave handles (ztile: 16 z) x (usub: 16 u) x all 64 w for one path.
// XH: hoist x2 into registers (16*N1 floats); off for N1==5 && K1>=3 paths
// (acc is 48-80 regs there; hoisting would spill).
template <int M1, int N1, int K1, int S1, int UC, bool XH>
__device__ __forceinline__ void run_path1(const float* __restrict__ x1g,
                                          const float* __restrict__ x2g,
                                          const unsigned short* __restrict__ Wbp,
                                          const float* __restrict__ Cg,
                                          float* __restrict__ partp,
                                          int local, char* __restrict__ smem)
{
    constexpr int KN    = K1 * N1;
    constexpr int NC    = K1;                // col-tiles = 16*K1/16
    constexpr int SST   = UC * S1 + 4;       // sc1 z-stride (floats)
    constexpr int TROWS = 16 * K1;           // sT rows
    constexpr int TOT   = 16 * UC * KN;      // slab elements per refill

    float*          sC  = (float*)smem;                         // [<=125]
    float*          sc1 = (float*)(smem + 512);                 // [16][SST]
    unsigned short* sT  = (unsigned short*)(smem + 512 + 16 * SST * 4);
    // sT: single buffer TROWS x 72 bf16

    const int t = threadIdx.x;               // == lane (64 threads)
    const int ln = t & 15, q = t >> 4;
    const int ztile = local >> 2, usub = local & 3;
    const int z0 = ztile * 16, u0 = usub * 16;

    for (int i = t; i < M1 * N1 * K1; i += TP_THREADS) sC[i] = Cg[i];
    __syncthreads();                         // 1-wave: trivial

    // c1 slab for u in [u0+us0, u0+us0+UC)
    auto build_slab = [&](int us0) {
        for (int i = t; i < TOT; i += TP_THREADS) {
            int z   = i / (UC * KN);
            int r   = i - z * (UC * KN);
            int uu2 = r / KN;
            int j   = r - uu2 * KN;
            int k   = j / N1, n = j - k * N1;
            const float* x1r = x1g + ((size_t)(z0 + z) * 64 + u0 + us0 + uu2) * M1;
            float s = 0.f;
#pragma unroll
            for (int m = 0; m < M1; ++m) s += x1r[m] * sC[(m * N1 + n) * K1 + k];
            sc1[z * SST + uu2 * S1 + j] = s;
        }
    };

    // x2 for this lane's v across the block's 16 z (hoisted when it fits)
    float xr[XH ? 16 : 1][N1];
    if constexpr (XH) {
#pragma unroll
        for (int z = 0; z < 16; ++z) {
            const float* xp = x2g + ((size_t)(z0 + z) * 64 + t) * N1;
#pragma unroll
            for (int n = 0; n < N1; ++n) xr[z][n] = xp[n];
        }
    }

    // T-form u into sT (single buffer; wave-local ordering via syncthreads)
    auto tform = [&](int uf) {
        const int uus = uf & (UC - 1);
#pragma unroll
        for (int z = 0; z < 16; ++z) {
            const float4* cp = (const float4*)&sc1[z * SST + uus * S1];
            float c1v[S1];
#pragma unroll
            for (int jj = 0; jj < S1 / 4; ++jj) {
                float4 f = cp[jj];
                c1v[jj * 4 + 0] = f.x; c1v[jj * 4 + 1] = f.y;
                c1v[jj * 4 + 2] = f.z; c1v[jj * 4 + 3] = f.w;
            }
            float xv[N1];
            if constexpr (XH) {
#pragma unroll
                for (int n = 0; n < N1; ++n) xv[n] = xr[z][n];
            } else {
                const float* xp = x2g + ((size_t)(z0 + z) * 64 + t) * N1;
#pragma unroll
                for (int n = 0; n < N1; ++n) xv[n] = xp[n];
            }
#pragma unroll
            for (int k = 0; k < K1; ++k) {
                float s = 0.f;
#pragma unroll
                for (int n = 0; n < N1; ++n) s += xv[n] * c1v[k * N1 + n];
                sT[(z * K1 + k) * 72 + t] = f2bf(s);
            }
        }
    };

    f32x4 acc[4][NC];
#pragma unroll
    for (int wt = 0; wt < 4; ++wt)
#pragma unroll
        for (int ci = 0; ci < NC; ++ci) acc[wt][ci] = (f32x4){0.f, 0.f, 0.f, 0.f};

    for (int uu = 0; uu < 16; ++uu) {
        if ((uu & (UC - 1)) == 0) {
            build_slab(uu);
            __syncthreads();
        }

        // A-frags for this u (L2); issued before tform so latency hides
        const unsigned short* wsrc = Wbp + (size_t)(u0 + uu) * 4096;
        s16x8 areg[4][2];
#pragma unroll
        for (int wt = 0; wt < 4; ++wt)
#pragma unroll
            for (int s2 = 0; s2 < 2; ++s2)
                areg[wt][s2] = *(const s16x8*)(wsrc + (wt * 16 + ln) * 64 + s2 * 32 + q * 8);

        tform(uu);
        __syncthreads();

        // MFMA: NC col-tiles x 4 w-tiles x 2 k-halves (acc not read until epilogue
        // -> the matrix pipe drains while the wave proceeds to the next u's VALU)
#pragma unroll
        for (int ci = 0; ci < NC; ++ci) {
            const unsigned short* tb = sT + (ci * 16 + ln) * 72;
            s16x8 bf0 = *(const s16x8*)(tb + q * 8);
            s16x8 bf1 = *(const s16x8*)(tb + 32 + q * 8);
#pragma unroll
            for (int wt = 0; wt < 4; ++wt) {
                acc[wt][ci] = __builtin_amdgcn_mfma_f32_16x16x32_bf16(
                    areg[wt][0], bf0, acc[wt][ci], 0, 0, 0);
                acc[wt][ci] = __builtin_amdgcn_mfma_f32_16x16x32_bf16(
                    areg[wt][1], bf1, acc[wt][ci], 0, 0, 0);
            }
        }
        __syncthreads();   // sT overwrite guard (trivial for 1 wave)
    }

    // ---- epilogue: transposed partials [us][k][z][w], contiguous float4
#pragma unroll
    for (int wt = 0; wt < 4; ++wt)
#pragma unroll
        for (int ci = 0; ci < NC; ++ci) {
            const int col = ci * 16 + ln;
            const int z = col / K1, k = col - z * K1;
            float* op = partp + ((size_t)(usub * K1 + k) * 1024 + z0 + z) * 64
                        + wt * 16 + q * 4;
            *(f32x4*)op = acc[wt][ci];
        }
}

__global__ __launch_bounds__(TP_THREADS, 2) void tp_main(KArgs a)
{
    __shared__ __align__(16) char smem[SMEM_BYTES];

    // uniform: 256 blocks per path (64 ztiles x 4 usub), heavy paths first
    const int pi = blockIdx.x >> 8;
    const int local = blockIdx.x & 255;

    // LDS/path = 512 + 16*SST*4 + TROWS*144:
    //  p2/p10: 15872  p5: 14336  p7: 13312  p6: 9728  p1/p8: 8704+..
    //  all <= 15872 -> 10 blocks/CU cap (VGPR caps at 8)
    switch (pi) {             //  M1 N1 K1 S1 UC XH
        case 0:  run_path1<1,5,5,28,2,false>(a.x1[0], a.x2[2], a.Wb + (size_t) 2*262144, a.C[2],  a.part[2],  local, smem); break;
        case 1:  run_path1<5,5,5,28,2,false>(a.x1[2], a.x2[2], a.Wb + (size_t)10*262144, a.C[10], a.part[10], local, smem); break;
        case 2:  run_path1<3,3,5,16,2,true >(a.x1[1], a.x2[1], a.Wb + (size_t) 5*262144, a.C[5],  a.part[5],  local, smem); break;
        case 3:  run_path1<5,1,5, 8,2,true >(a.x1[2], a.x2[0], a.Wb + (size_t) 7*262144, a.C[7],  a.part[7],  local, smem); break;
        case 4:  run_path1<3,5,3,16,2,false>(a.x1[1], a.x2[2], a.Wb + (size_t) 6*262144, a.C[6],  a.part[6],  local, smem); break;
        case 5:  run_path1<1,3,3,12,2,true >(a.x1[0], a.x2[1], a.Wb + (size_t) 1*262144, a.C[1],  a.part[1],  local, smem); break;
        case 6:  run_path1<5,3,3,12,2,true >(a.x1[2], a.x2[1], a.Wb + (size_t) 8*262144, a.C[8],  a.part[8],  local, smem); break;
        case 7:  run_path1<3,1,3, 4,2,true >(a.x1[1], a.x2[0], a.Wb + (size_t) 3*262144, a.C[3],  a.part[3],  local, smem); break;
        case 8:  run_path1<5,5,1, 8,2,true >(a.x1[2], a.x2[2], a.Wb + (size_t) 9*262144, a.C[9],  a.part[9],  local, smem); break;
        case 9:  run_path1<3,3,1, 4,2,true >(a.x1[1], a.x2[1], a.Wb + (size_t) 4*262144, a.C[4],  a.part[4],  local, smem); break;
        case 10: run_path1<1,1,1, 4,2,true >(a.x1[0], a.x2[0], a.Wb + (size_t) 0*262144, a.C[0],  a.part[0],  local, smem); break;
        default: break;
    }
}

// ---------------- reduce: sum partials into out[z][w][9] ----------------
// partials [us][k][1024 z][64 w] per path -> lane-coalesced loads (w = lane).

struct RArgs {
    const float* part[11];
    float*       out;
};

__global__ __launch_bounds__(NTHREADS) void reduce_out(RArgs r)
{
    __shared__ float red[3 * 64 * 9];
    const int lane = threadIdx.x & 63, us = threadIdx.x >> 6;
    const int zw = blockIdx.x * 64 + lane;      // z*64+w
    const int z = zw >> 6, w = zw & 63;

    float o[9];
#pragma unroll
    for (int i = 0; i < 9; ++i) o[i] = 0.f;

    {   // l3=0 (slot 0), paths {0,4,9}, K1=1
        const int P[3] = {0, 4, 9};
#pragma unroll
        for (int pi = 0; pi < 3; ++pi)
            o[0] += r.part[P[pi]][((size_t)us * 1024 + z) * 64 + w];
    }
    {   // l3=1 (slots 1..3), paths {1,3,6,8}, K1=3
        const int P[4] = {1, 3, 6, 8};
#pragma unroll
        for (int pi = 0; pi < 4; ++pi) {
            const float* pp = r.part[P[pi]];
#pragma unroll
            for (int k = 0; k < 3; ++k)
                o[1 + k] += pp[((size_t)(us * 3 + k) * 1024 + z) * 64 + w];
        }
    }
    {   // l3=2 (slots 4..8), paths {2,5,7,10}, K1=5
        const int P[4] = {2, 5, 7, 10};
#pragma unroll
        for (int pi = 0; pi < 4; ++pi) {
            const float* pp = r.part[P[pi]];
#pragma unroll
            for (int k = 0; k < 5; ++k)
                o[4 + k] += pp[((size_t)(us * 5 + k) * 1024 + z) * 64 + w];
        }
    }

    if (us > 0) {
#pragma unroll
        for (int i = 0; i < 9; ++i) red[((us - 1) * 64 + lane) * 9 + i] = o[i];
    }
    __syncthreads();
    if (us == 0) {
#pragma unroll
        for (int i = 0; i < 9; ++i)
            o[i] += red[(0 * 64 + lane) * 9 + i]
                  + red[(1 * 64 + lane) * 9 + i]
                  + red[(2 * 64 + lane) * 9 + i];
        float* op = r.out + (size_t)zw * 9;
#pragma unroll
        for (int i = 0; i < 9; ++i) op[i] = o[i];
    }
}

// ---------------- launch ----------------

extern "C" void kernel_launch(void* const* d_in, const int* in_sizes, int n_in,
                              void* d_out, int out_size, void* d_ws, size_t ws_size,
                              hipStream_t stream)
{
    static const int cumK1[11] = {0, 1, 4, 9, 12, 13, 18, 21, 26, 29, 30}; // prefix of K1

    unsigned short* Wb = (unsigned short*)d_ws;                       // 5.77 MB
    float* partbase = (float*)((char*)d_ws + (6u << 20));             // 30.7 MB

    KArgs a;
    // dict order: x1_l0, x2_l0, x1_l1, x2_l1, x1_l2, x2_l2, W, C_0..C_10
    a.x1[0] = (const float*)d_in[0];
    a.x2[0] = (const float*)d_in[1];
    a.x1[1] = (const float*)d_in[2];
    a.x2[1] = (const float*)d_in[3];
    a.x1[2] = (const float*)d_in[4];
    a.x2[2] = (const float*)d_in[5];
    a.Wb = Wb;
    RArgs rr;
    for (int p = 0; p < 11; ++p) {
        a.C[p]    = (const float*)d_in[7 + p];
        a.part[p] = partbase + (size_t)cumK1[p] * 262144;   // 4*K1*1024*64 per path
        rr.part[p] = a.part[p];
    }
    rr.out = (float*)d_out;

    prep_w<<<dim3(720896 / NTHREADS), NTHREADS, 0, stream>>>((const float*)d_in[6], Wb);
    tp_main<<<dim3(2816), TP_THREADS, 0, stream>>>(a);
    reduce_out<<<dim3(1024), NTHREADS, 0, stream>>>(rr);
}

// Round 8
// 171.986 us; speedup vs baseline: 1.1531x; 1.1531x over previous
//
#include <hip/hip_runtime.h>

// HarmonicFullyConnectedTensorProduct, lmax=2, MUL=64, B=1024, 11 paths.
// out[z,w,k] += sum_{u,v,m,n} x1[z,u,m] x2[z,v,n] W[p,w,u,v] C_p[m,n,k]
//
// Round 16: R13 (best: 174.6us, tp 83us) with UNIFORM ZT=16 for all paths.
// Evidence chain: R13 cap 4->5 blk/CU: occ flat ~35% -> not LDS-capped.
// R14 barrier-merge (54KB LDS): occ 19%, tp 99 -> worse. R15 1-wave blocks:
// occ 14%, tp 103 -> TLP collapse. Conclusion: latency-bound at ~2.8
// waves/SIMD because the GRID is shallow (2048 blk = 8/CU) with a ragged
// ZT32 tail. Fix: ZT=16 everywhere (NC=K1 odd -> proven ROWT=1 path;
// p6 already ran ZT16/K1=3 in R13) -> 2816 uniform blocks (11/CU), all
// paths LDS <= 32000 -> exactly 5 blocks/CU. Code otherwise identical
// to R13 (same templates, tform, epilogue, reduce, prep).

#define NTHREADS 256
#define SMEM_BYTES 32768

typedef __attribute__((ext_vector_type(4))) float f32x4;
typedef __attribute__((ext_vector_type(8))) short s16x8;

__device__ __forceinline__ unsigned short f2bf(float x) {
    __bf16 b = (__bf16)x;
    union { __bf16 h; unsigned short u; } v;
    v.h = b;
    return v.u;
}

// ---------------- prep: W fp32 [p][w][u][v] -> bf16 [p][u][w][v] ----------------

__global__ __launch_bounds__(NTHREADS) void prep_w(const float* __restrict__ W,
                                                   unsigned short* __restrict__ Wb)
{
    int id = blockIdx.x * NTHREADS + threadIdx.x;   // (p,u,w,v4): 11*64*64*16
    int v4 = (id & 15) << 2;
    int w  = (id >> 4) & 63;
    int u  = (id >> 10) & 63;
    int p  = id >> 16;
    float4 f = *(const float4*)(W + (((size_t)p * 64 + w) * 64 + u) * 64 + v4);
    ushort4 h;
    h.x = f2bf(f.x); h.y = f2bf(f.y); h.z = f2bf(f.z); h.w = f2bf(f.w);
    *(ushort4*)(Wb + (((size_t)p * 64 + u) * 64 + w) * 64 + v4) = h;
}

// ---------------- main ----------------

struct KArgs {
    const float*          x1[3];
    const float*          x2[3];
    const unsigned short* Wb;
    const float*          C[11];
    float*                part[11];   // per-path partials [4 usub][K1][1024][64]
};

template <int M1, int N1, int K1, int ZT, int S1, int UC>
__device__ __forceinline__ void run_path(const float* __restrict__ x1g,
                                         const float* __restrict__ x2g,
                                         const unsigned short* __restrict__ Wbp,
                                         const float* __restrict__ Cg,
                                         float* __restrict__ partp,
                                         int local, char* __restrict__ smem)
{
    constexpr int KN   = K1 * N1;
    constexpr int NC   = ZT * K1 / 16;        // MFMA col-tiles
    constexpr bool EVEN = (NC % 2 == 0);
    constexpr int ROWT = EVEN ? 2 : 1;        // w-tiles per wave
    constexpr int COLT = EVEN ? NC / 2 : NC;  // col-tiles per wave
    constexpr int NI   = ZT / 4;              // T-form z-iters
    constexpr int SST  = UC * S1 + 4;         // sc1 z-stride (floats)
    constexpr int TROWS = ZT * K1;

    float*          sC  = (float*)smem;                        // [<=125]
    float*          sc1 = (float*)(smem + 512);                // [ZT][SST]
    unsigned short* sT0 = (unsigned short*)(smem + 512 + ZT * SST * 4);
    // sT0: 2 buffers x TROWS x 72 bf16

    const int t = threadIdx.x, lane = t & 63, wave = t >> 6;
    const int ln = lane & 15, q = lane >> 4;
    const int ztile = local >> 2, usub = local & 3;
    const int z0 = ztile * ZT, u0 = usub * 16;

    for (int i = t; i < M1 * N1 * K1; i += NTHREADS) sC[i] = Cg[i];
    __syncthreads();

    // cooperative c1 slab build: sc1[z][uu2*S1 + k*N1+n] for u in [u0+us0, +UC)
    auto build_slab = [&](int us0) {
        for (int i = t; i < ZT * UC * KN; i += NTHREADS) {
            int z   = i / (UC * KN);
            int r   = i - z * (UC * KN);
            int uu2 = r / KN;
            int j   = r - uu2 * KN;
            int k   = j / N1, n = j - k * N1;
            const float* x1r = x1g + ((size_t)(z0 + z) * 64 + u0 + us0 + uu2) * M1;
            float s = 0.f;
#pragma unroll
            for (int m = 0; m < M1; ++m) s += x1r[m] * sC[(m * N1 + n) * K1 + k];
            sc1[z * SST + uu2 * S1 + j] = s;
        }
    };

    // x2 for this thread's (z = i*4+wave, v = lane), reused across all u
    float xr[NI][N1];
#pragma unroll
    for (int i = 0; i < NI; ++i) {
        const float* xp = x2g + ((size_t)(z0 + i * 4 + wave) * 64 + lane) * N1;
#pragma unroll
        for (int n = 0; n < N1; ++n) xr[i][n] = xp[n];
    }

    // T-form for u-offset uf into buffer sTn
    auto tform = [&](int uf, unsigned short* sTn) {
        const int uus = uf & (UC - 1);
#pragma unroll
        for (int i = 0; i < NI; ++i) {
            const int z = i * 4 + wave;                 // wave-uniform
            const float4* cp = (const float4*)&sc1[z * SST + uus * S1];
            float c1v[S1];
#pragma unroll
            for (int jj = 0; jj < S1 / 4; ++jj) {
                float4 f = cp[jj];
                c1v[jj * 4 + 0] = f.x; c1v[jj * 4 + 1] = f.y;
                c1v[jj * 4 + 2] = f.z; c1v[jj * 4 + 3] = f.w;
            }
#pragma unroll
            for (int k = 0; k < K1; ++k) {
                float s = 0.f;
#pragma unroll
                for (int n = 0; n < N1; ++n) s += xr[i][n] * c1v[k * N1 + n];
                sTn[(z * K1 + k) * 72 + lane] = f2bf(s);
            }
        }
    };

    f32x4 acc[ROWT][COLT];
#pragma unroll
    for (int rt = 0; rt < ROWT; ++rt)
#pragma unroll
        for (int ci = 0; ci < COLT; ++ci) acc[rt][ci] = (f32x4){0.f, 0.f, 0.f, 0.f};

    build_slab(0);
    __syncthreads();
    tform(0, sT0);
    __syncthreads();

#pragma unroll 2
    for (int uu = 0; uu < 16; ++uu) {
        if (((uu + 1) & (UC - 1)) == 0 && (uu + 1) < 16) {
            // refill sc1 for next slab; prior readers finished before last barrier
            build_slab(uu + 1);
            __syncthreads();
        }
        const int cur = uu & 1;
        unsigned short* sTc = sT0 + cur * (TROWS * 72);
        unsigned short* sTn = sT0 + (cur ^ 1) * (TROWS * 72);

        // A-frags for THIS u straight from L2 (issued early = in-iter prefetch)
        const unsigned short* wsrc = Wbp + (size_t)(u0 + uu) * 4096;
        s16x8 areg[ROWT][2];
#pragma unroll
        for (int rt = 0; rt < ROWT; ++rt) {
            const int wt = EVEN ? ((wave >> 1) * 2 + rt) : wave;
#pragma unroll
            for (int s2 = 0; s2 < 2; ++s2)
                areg[rt][s2] = *(const s16x8*)(wsrc + (wt * 16 + ln) * 64 + s2 * 32 + q * 8);
        }

        // T-form next u (writes sTn) — overlaps with MFMA below in the pipes
        if (uu < 15) tform(uu + 1, sTn);

        // MFMA from sTc
#pragma unroll
        for (int ci = 0; ci < COLT; ++ci) {
            const int c = EVEN ? ((wave & 1) * COLT + ci) : ci;
            s16x8 bf0 = *(const s16x8*)&sTc[(c * 16 + ln) * 72 + q * 8];
            s16x8 bf1 = *(const s16x8*)&sTc[(c * 16 + ln) * 72 + 32 + q * 8];
#pragma unroll
            for (int rt = 0; rt < ROWT; ++rt) {
                acc[rt][ci] = __builtin_amdgcn_mfma_f32_16x16x32_bf16(
                    areg[rt][0], bf0, acc[rt][ci], 0, 0, 0);
                acc[rt][ci] = __builtin_amdgcn_mfma_f32_16x16x32_bf16(
                    areg[rt][1], bf1, acc[rt][ci], 0, 0, 0);
            }
        }
        __syncthreads();
    }

    // ---- epilogue: transposed partials [us][k][z][w]; w is the acc fast axis
#pragma unroll
    for (int rt = 0; rt < ROWT; ++rt) {
        const int wt = EVEN ? ((wave >> 1) * 2 + rt) : wave;
#pragma unroll
        for (int ci = 0; ci < COLT; ++ci) {
            const int c = EVEN ? ((wave & 1) * COLT + ci) : ci;
            const int col = c * 16 + ln;
            const int z = col / K1, k = col - z * K1;
            float* op = partp + ((size_t)(usub * K1 + k) * 1024 + z0 + z) * 64
                        + wt * 16 + q * 4;
            *(f32x4*)op = acc[rt][ci];
        }
    }
}

__global__ __launch_bounds__(NTHREADS, 5) void tp_main(KArgs a)
{
    __shared__ __align__(16) char smem[SMEM_BYTES];

    // uniform 256 blocks per path (64 ztiles x 4 usub), heavy paths first
    const int pi = blockIdx.x >> 8;
    const int local = blockIdx.x & 255;

    // LDS/path = 512 + 16*SST*4 + 2*16*K1*144:
    //  p2/p10: 30976  p5: 32000  p7: 32000  p6: 22784  p1/p8: 20992
    //  p3: 18704  p9: 13568  p4/p0: 9488   (max 32000 -> 5 blocks/CU)
    switch (pi) {             //  M1 N1 K1 ZT S1 UC
        case 0:  run_path<1,5,5,16,28, 4>(a.x1[0], a.x2[2], a.Wb + (size_t) 2*262144, a.C[2],  a.part[2],  local, smem); break;
        case 1:  run_path<5,5,5,16,28, 4>(a.x1[2], a.x2[2], a.Wb + (size_t)10*262144, a.C[10], a.part[10], local, smem); break;
        case 2:  run_path<3,3,5,16,16, 8>(a.x1[1], a.x2[1], a.Wb + (size_t) 5*262144, a.C[5],  a.part[5],  local, smem); break;
        case 3:  run_path<5,1,5,16, 8,16>(a.x1[2], a.x2[0], a.Wb + (size_t) 7*262144, a.C[7],  a.part[7],  local, smem); break;
        case 4:  run_path<3,5,3,16,16, 8>(a.x1[1], a.x2[2], a.Wb + (size_t) 6*262144, a.C[6],  a.part[6],  local, smem); break;
        case 5:  run_path<1,3,3,16,12, 8>(a.x1[0], a.x2[1], a.Wb + (size_t) 1*262144, a.C[1],  a.part[1],  local, smem); break;
        case 6:  run_path<5,3,3,16,12, 8>(a.x1[2], a.x2[1], a.Wb + (size_t) 8*262144, a.C[8],  a.part[8],  local, smem); break;
        case 7:  run_path<3,1,3,16, 4,16>(a.x1[1], a.x2[0], a.Wb + (size_t) 3*262144, a.C[3],  a.part[3],  local, smem); break;
        case 8:  run_path<5,5,1,16, 8,16>(a.x1[2], a.x2[2], a.Wb + (size_t) 9*262144, a.C[9],  a.part[9],  local, smem); break;
        case 9:  run_path<3,3,1,16, 4,16>(a.x1[1], a.x2[1], a.Wb + (size_t) 4*262144, a.C[4],  a.part[4],  local, smem); break;
        case 10: run_path<1,1,1,16, 4,16>(a.x1[0], a.x2[0], a.Wb + (size_t) 0*262144, a.C[0],  a.part[0],  local, smem); break;
        default: break;
    }
}

// ---------------- reduce: sum partials into out[z][w][9] ----------------
// partials [us][k][1024 z][64 w] per path -> lane-coalesced loads (w = lane).

struct RArgs {
    const float* part[11];
    float*       out;
};

__global__ __launch_bounds__(NTHREADS) void reduce_out(RArgs r)
{
    __shared__ float red[3 * 64 * 9];
    const int lane = threadIdx.x & 63, us = threadIdx.x >> 6;
    const int zw = blockIdx.x * 64 + lane;      // z*64+w
    const int z = zw >> 6, w = zw & 63;

    float o[9];
#pragma unroll
    for (int i = 0; i < 9; ++i) o[i] = 0.f;

    {   // l3=0 (slot 0), paths {0,4,9}, K1=1
        const int P[3] = {0, 4, 9};
#pragma unroll
        for (int pi = 0; pi < 3; ++pi)
            o[0] += r.part[P[pi]][((size_t)us * 1024 + z) * 64 + w];
    }
    {   // l3=1 (slots 1..3), paths {1,3,6,8}, K1=3
        const int P[4] = {1, 3, 6, 8};
#pragma unroll
        for (int pi = 0; pi < 4; ++pi) {
            const float* pp = r.part[P[pi]];
#pragma unroll
            for (int k = 0; k < 3; ++k)
                o[1 + k] += pp[((size_t)(us * 3 + k) * 1024 + z) * 64 + w];
        }
    }
    {   // l3=2 (slots 4..8), paths {2,5,7,10}, K1=5
        const int P[4] = {2, 5, 7, 10};
#pragma unroll
        for (int pi = 0; pi < 4; ++pi) {
            const float* pp = r.part[P[pi]];
#pragma unroll
            for (int k = 0; k < 5; ++k)
                o[4 + k] += pp[((size_t)(us * 5 + k) * 1024 + z) * 64 + w];
        }
    }

    if (us > 0) {
#pragma unroll
        for (int i = 0; i < 9; ++i) red[((us - 1) * 64 + lane) * 9 + i] = o[i];
    }
    __syncthreads();
    if (us == 0) {
#pragma unroll
        for (int i = 0; i < 9; ++i)
            o[i] += red[(0 * 64 + lane) * 9 + i]
                  + red[(1 * 64 + lane) * 9 + i]
                  + red[(2 * 64 + lane) * 9 + i];
        float* op = r.out + (size_t)zw * 9;
#pragma unroll
        for (int i = 0; i < 9; ++i) op[i] = o[i];
    }
}

// ---------------- launch ----------------

extern "C" void kernel_launch(void* const* d_in, const int* in_sizes, int n_in,
                              void* d_out, int out_size, void* d_ws, size_t ws_size,
                              hipStream_t stream)
{
    static const int cumK1[11] = {0, 1, 4, 9, 12, 13, 18, 21, 26, 29, 30}; // prefix of K1

    unsigned short* Wb = (unsigned short*)d_ws;                       // 5.77 MB
    float* partbase = (float*)((char*)d_ws + (6u << 20));             // 30.7 MB

    KArgs a;
    // dict order: x1_l0, x2_l0, x1_l1, x2_l1, x1_l2, x2_l2, W, C_0..C_10
    a.x1[0] = (const float*)d_in[0];
    a.x2[0] = (const float*)d_in[1];
    a.x1[1] = (const float*)d_in[2];
    a.x2[1] = (const float*)d_in[3];
    a.x1[2] = (const float*)d_in[4];
    a.x2[2] = (const float*)d_in[5];
    a.Wb = Wb;
    RArgs rr;
    for (int p = 0; p < 11; ++p) {
        a.C[p]    = (const float*)d_in[7 + p];
        a.part[p] = partbase + (size_t)cumK1[p] * 262144;   // 4*K1*1024*64 per path
        rr.part[p] = a.part[p];
    }
    rr.out = (float*)d_out;

    prep_w<<<dim3(720896 / NTHREADS), NTHREADS, 0, stream>>>((const float*)d_in[6], Wb);
    tp_main<<<dim3(2816), NTHREADS, 0, stream>>>(a);
    reduce_out<<<dim3(1024), NTHREADS, 0, stream>>>(rr);
}